// Round 4
// baseline (567.384 us; speedup 1.0000x reference)
//
#include <hip/hip_runtime.h>
#include <hip/hip_bf16.h>
#include <math.h>

// Problem constants (fixed by the reference)
#define B_SZ   16
#define SRC_N  512
#define N_TOT  16384
#define P_PTS  128
#define FEAT   256
#define EMB    100
#define OUT_C  200   // EMB (sg) + EMB (pt)

typedef __attribute__((ext_vector_type(8))) short short8;
typedef __attribute__((ext_vector_type(8))) unsigned short ushort8;
typedef __attribute__((ext_vector_type(4))) float floatx4;

__device__ __forceinline__ unsigned short f2bf(float x) {   // RNE, scalar
    union { float f; unsigned u; } v; v.f = x;
    unsigned r = v.u + 0x7fffu + ((v.u >> 16) & 1u);
    return (unsigned short)(r >> 16);
}
// pack two f32 -> bf16x2 dword, RNE
__device__ __forceinline__ unsigned pack_rne(float a, float b) {
    union { float f; unsigned u; } x, y; x.f = a; y.f = b;
    unsigned lo = x.u + 0x7fffu + ((x.u >> 16) & 1u);
    unsigned hi = y.u + 0x7fffu + ((y.u >> 16) & 1u);
    return __builtin_amdgcn_perm(hi, lo, 0x07060302);
}
// pack two f32 -> bf16x2 dword, round-half-up (3 ops)
__device__ __forceinline__ unsigned pack_rhu(float a, float b) {
    union { float f; unsigned u; } x, y; x.f = a; y.f = b;
    return __builtin_amdgcn_perm(y.u + 0x8000u, x.u + 0x8000u, 0x07060302);
}

// d_ws layout (unsigned short elements)
#define WS_PW2T 0        // pointnet w2T [128][64]   w2T[n][k]=w2[k][n]
#define WS_PW3T 8192     // pointnet w3T [256][128]
#define WS_POET 40960    // pointnet oeT [100][256]  oeT[j][c]=oe_w[c][j]
#define WS_SGW1 66560    // sgnet w1T    [256][256]  (k natural)
#define WS_SGW2 132096   // sgnet w2Tp   [256][256]  k' permuted (perm32)
#define WS_SGSE 197632   // sgnet seTp   [112][256]  k' permuted, zero-pad j>=100
#define WS_TOT  226304

__device__ __forceinline__ int perm32(int p) {   // stored pos -> actual channel
    return 32 * (p >> 5) + 16 * (p & 1) + ((p >> 1) & 15);
}

__global__ void prep_kernel(const float* __restrict__ pw2,
                            const float* __restrict__ pw3,
                            const float* __restrict__ oew,
                            const float* __restrict__ sw1,
                            const float* __restrict__ sw2,
                            const float* __restrict__ sew,
                            unsigned short* __restrict__ ws) {
    const int o = blockIdx.x * 256 + threadIdx.x;
    if (o < WS_PW3T) {
        const int n = o >> 6, k = o & 63;
        ws[o] = f2bf(pw2[k * 128 + n]);
    } else if (o < WS_POET) {
        const int i = o - WS_PW3T;
        const int n = i >> 7, k = i & 127;
        ws[o] = f2bf(pw3[k * 256 + n]);
    } else if (o < WS_SGW1) {
        const int i = o - WS_POET;
        const int j = i >> 8, c = i & 255;
        ws[o] = f2bf(oew[c * EMB + j]);
    } else if (o < WS_SGW2) {
        const int i = o - WS_SGW1;
        const int n = i >> 8, k = i & 255;
        ws[o] = f2bf(sw1[k * 256 + n]);
    } else if (o < WS_SGSE) {
        const int i = o - WS_SGW2;
        const int n = i >> 8, kp = i & 255;
        ws[o] = f2bf(sw2[perm32(kp) * 256 + n]);
    } else if (o < WS_TOT) {
        const int i = o - WS_SGSE;
        const int n = i >> 8, kp = i & 255;
        ws[o] = (n < EMB) ? f2bf(sew[perm32(kp) * EMB + n]) : (unsigned short)0;
    }
}

#define SXS 264   // sgnet activation row stride (shorts)
#define H1S 72    // pointnet h1 row stride (shorts)
#define H2S 136   // pointnet h2 row stride (shorts)
#define SMEM_BYTES 35840   // max(sgnet 33792, pointnet 18432+17408)

// ---------------------------------------------------------------------------
// sgnet device body (MFMA). M=32 rows/block. Activations stored with perm32
// channel permutation; next layer's weights carry matching K-permutation.
// ---------------------------------------------------------------------------
template <bool RELU>
__device__ __forceinline__ void sg_layer(const unsigned short* s_in,
                                         unsigned short* s_out,
                                         const unsigned short* wT,
                                         const float* __restrict__ bias,
                                         int wave, int lm, int lq) {
#pragma unroll
    for (int np = 0; np < 2; np++) {
        short8 bf[2][8];
        float bv[2];
#pragma unroll
        for (int b = 0; b < 2; b++) {
            const int n = wave * 64 + (2 * np + b) * 16 + lm;
            bv[b] = bias[n];
#pragma unroll
            for (int kc = 0; kc < 8; kc++)
                bf[b][kc] = *(const short8*)&wT[n * 256 + kc * 32 + lq * 8];
        }
        floatx4 acc[2][2];
#pragma unroll
        for (int b = 0; b < 2; b++)
#pragma unroll
            for (int mt = 0; mt < 2; mt++) acc[b][mt] = {0.f, 0.f, 0.f, 0.f};
#pragma unroll
        for (int mt = 0; mt < 2; mt++) {
            short8 af[8];
#pragma unroll
            for (int kc = 0; kc < 8; kc++)
                af[kc] = *(const short8*)&s_in[(mt * 16 + lm) * SXS + kc * 32 + lq * 8];
#pragma unroll
            for (int b = 0; b < 2; b++)
#pragma unroll
                for (int kc = 0; kc < 8; kc++)
                    acc[b][mt] = __builtin_amdgcn_mfma_f32_16x16x32_bf16(
                        af[kc], bf[b][kc], acc[b][mt], 0, 0, 0);
        }
#pragma unroll
        for (int mt = 0; mt < 2; mt++)
#pragma unroll
            for (int r = 0; r < 4; r++) {
                float v0 = acc[0][mt][r] + bv[0];
                float v1 = acc[1][mt][r] + bv[1];
                if (RELU) { v0 = fmaxf(v0, 0.f); v1 = fmaxf(v1, 0.f); }
                *(unsigned*)&s_out[(mt * 16 + lq * 4 + r) * SXS +
                                   wave * 64 + 32 * np + 2 * lm] = pack_rne(v0, v1);
            }
    }
}

__device__ void sgnet_body(unsigned char* smem, int blk,
                           const float* __restrict__ src_feat,
                           const float* __restrict__ ref_feat,
                           const float* __restrict__ b1,
                           const float* __restrict__ b2,
                           const float* __restrict__ seb,
                           const unsigned short* __restrict__ ws,
                           float* __restrict__ out)
{
    unsigned short* s_x = (unsigned short*)smem;            // 32*SXS
    unsigned short* s_h = s_x + 32 * SXS;                   // 32*SXS

    const unsigned short* w1T = ws + WS_SGW1;
    const unsigned short* w2T = ws + WS_SGW2;
    const unsigned short* seT = ws + WS_SGSE;

    const bool is_ref = (blk >= 256);
    const int row0 = (blk & 255) * 32;
    const float* feat = is_ref ? ref_feat : src_feat;
    const int t = threadIdx.x;
    const int wave = t >> 6, lane = t & 63, lm = lane & 15, lq = lane >> 4;

#pragma unroll
    for (int i = 0; i < 4; i++) {
        const int flat = i * 2048 + t * 8;
        const int r = flat >> 8, c = flat & 255;
        const float4 a = *(const float4*)&feat[(row0 + r) * 256 + c];
        const float4 b = *(const float4*)&feat[(row0 + r) * 256 + c + 4];
        uint4 d;
        d.x = pack_rne(a.x, a.y); d.y = pack_rne(a.z, a.w);
        d.z = pack_rne(b.x, b.y); d.w = pack_rne(b.z, b.w);
        *(uint4*)&s_x[r * SXS + c] = d;
    }
    __syncthreads();

    sg_layer<true>(s_x, s_h, w1T, b1, wave, lm, lq);
    __syncthreads();
    sg_layer<false>(s_h, s_x, w2T, b2, wave, lm, lq);
    __syncthreads();

#pragma unroll
    for (int s = 0; s < 2; s++) {
        const int ntt = wave * 2 + s;
        if (ntt >= 7) continue;
        const int j = ntt * 16 + lm;     // < 112
        short8 bf[8];
#pragma unroll
        for (int kc = 0; kc < 8; kc++)
            bf[kc] = *(const short8*)&seT[j * 256 + kc * 32 + lq * 8];
        const float bj = (j < EMB) ? seb[j] : 0.f;
#pragma unroll
        for (int mt = 0; mt < 2; mt++) {
            short8 af[8];
#pragma unroll
            for (int kc = 0; kc < 8; kc++)
                af[kc] = *(const short8*)&s_x[(mt * 16 + lm) * SXS + kc * 32 + lq * 8];
            floatx4 acc = {0.f, 0.f, 0.f, 0.f};
#pragma unroll
            for (int kc = 0; kc < 8; kc++)
                acc = __builtin_amdgcn_mfma_f32_16x16x32_bf16(af[kc], bf[kc], acc, 0, 0, 0);
            if (j < EMB) {
#pragma unroll
                for (int r = 0; r < 4; r++) {
                    const int grow = row0 + mt * 16 + lq * 4 + r;
                    const int pos = ((grow >> 9) << 10) + (grow & 511) + (is_ref ? 512 : 0);
                    out[pos * OUT_C + j] = acc[r] + bj;
                }
            }
        }
    }
}

// ---------------------------------------------------------------------------
// pointnet device body (MFMA, weights-as-A, 2x 64-pt chunks for LDS).
// ---------------------------------------------------------------------------
__device__ void pointnet_body(unsigned char* smem, int obj,
                              const float* __restrict__ pts,
                              const float* __restrict__ w1,
                              const float* __restrict__ b1,
                              const float* __restrict__ b2,
                              const float* __restrict__ b3,
                              const unsigned short* __restrict__ ws,
                              const float* __restrict__ oeb,
                              float* __restrict__ out)
{
    unsigned short* s_h1 = (unsigned short*)smem;                 // 128*H1S = 18432 B
    unsigned short* s_h2 = (unsigned short*)(smem + 18432);       // 64*H2S  = 17408 B
    float* s_pts  = (float*)s_h2;               // h1 phase only (1536 B)
    float* s_tmp  = (float*)s_h1;               // [16][264] partial maxes
    float* s_feat = (float*)s_h1 + 16 * 264;    // [256]

    const unsigned short* w2T = ws + WS_PW2T;
    const unsigned short* w3T = ws + WS_PW3T;
    const unsigned short* oeT = ws + WS_POET;

    const int t = threadIdx.x;
    const int wave = t >> 6, lane = t & 63, lm = lane & 15, lq = lane >> 4;

    // prefetch h2 weights (A-frags) + bias vectors
    short8 w2f[2][2];
    float4 b2v[2];
#pragma unroll
    for (int mi = 0; mi < 2; mi++) {
        const int m = (wave * 2 + mi) * 16 + lm;
#pragma unroll
        for (int kc = 0; kc < 2; kc++)
            w2f[mi][kc] = *(const short8*)&w2T[m * 64 + kc * 32 + lq * 8];
        b2v[mi] = *(const float4*)&b2[(wave * 2 + mi) * 16 + lq * 4];
    }

    // stage points
    for (int i = t; i < P_PTS * 3; i += 256)
        s_pts[i] = pts[obj * (P_PTS * 3) + i];
    __syncthreads();

    // ---- h1: relu(pts @ w1 + b1) -> s_h1[pt][64ch] bf16 ----
    {
        const int k0 = (t & 7) * 8;
        float wr0[8], wr1[8], wr2[8], br[8];
#pragma unroll
        for (int j = 0; j < 8; j++) {
            wr0[j] = w1[k0 + j]; wr1[j] = w1[64 + k0 + j];
            wr2[j] = w1[128 + k0 + j]; br[j] = b1[k0 + j];
        }
#pragma unroll
        for (int i = 0; i < 4; i++) {
            const int m = (t >> 3) + i * 32;
            const float x = s_pts[m * 3 + 0];
            const float y = s_pts[m * 3 + 1];
            const float z = s_pts[m * 3 + 2];
            float v[8];
#pragma unroll
            for (int j = 0; j < 8; j++)
                v[j] = fmaxf(br[j] + x * wr0[j] + y * wr1[j] + z * wr2[j], 0.f);
            uint4 d;
            d.x = pack_rhu(v[0], v[1]); d.y = pack_rhu(v[2], v[3]);
            d.z = pack_rhu(v[4], v[5]); d.w = pack_rhu(v[6], v[7]);
            *(uint4*)&s_h1[m * H1S + k0] = d;
        }
    }

    // prefetch h3 weights (A-frags) while h1 drains
    short8 w3f[4][4];
#pragma unroll
    for (int mi = 0; mi < 4; mi++) {
        const int m = (wave * 4 + mi) * 16 + lm;
#pragma unroll
        for (int kc = 0; kc < 4; kc++)
            w3f[mi][kc] = *(const short8*)&w3T[m * 128 + kc * 32 + lq * 8];
    }

    floatx4 mx[4];
#pragma unroll
    for (int mi = 0; mi < 4; mi++) mx[mi] = {-1e30f, -1e30f, -1e30f, -1e30f};

    __syncthreads();   // s_pts dead; s_h2 writable

    // ---- chunk loop: 2 x 64 points ----
    for (int c = 0; c < 2; c++) {
        // h2: D[ch][pt] = w2T x h1^T; packed b64 stores -> s_h2[pt64][ch]
#pragma unroll
        for (int nt = 0; nt < 4; nt++) {
            short8 hf[2];
#pragma unroll
            for (int kc = 0; kc < 2; kc++)
                hf[kc] = *(const short8*)&s_h1[(c * 64 + nt * 16 + lm) * H1S + kc * 32 + lq * 8];
#pragma unroll
            for (int mi = 0; mi < 2; mi++) {
                floatx4 acc = {0.f, 0.f, 0.f, 0.f};
                acc = __builtin_amdgcn_mfma_f32_16x16x32_bf16(w2f[mi][0], hf[0], acc, 0, 0, 0);
                acc = __builtin_amdgcn_mfma_f32_16x16x32_bf16(w2f[mi][1], hf[1], acc, 0, 0, 0);
                const float v0 = fmaxf(acc[0] + b2v[mi].x, 0.f);
                const float v1 = fmaxf(acc[1] + b2v[mi].y, 0.f);
                const float v2 = fmaxf(acc[2] + b2v[mi].z, 0.f);
                const float v3 = fmaxf(acc[3] + b2v[mi].w, 0.f);
                uint2 dd;
                dd.x = pack_rhu(v0, v1);
                dd.y = pack_rhu(v2, v3);
                *(uint2*)&s_h2[(nt * 16 + lm) * H2S + (wave * 2 + mi) * 16 + lq * 4] = dd;
            }
        }
        __syncthreads();   // h2 chunk visible (and, for c=1, s_h1 reads done)

        // h3: D[out][pt] = w3T x h2^T; running max
#pragma unroll
        for (int nt = 0; nt < 4; nt++) {
            short8 hf[4];
#pragma unroll
            for (int kc = 0; kc < 4; kc++)
                hf[kc] = *(const short8*)&s_h2[(nt * 16 + lm) * H2S + kc * 32 + lq * 8];
#pragma unroll
            for (int mi = 0; mi < 4; mi++) {
                floatx4 acc = {0.f, 0.f, 0.f, 0.f};
#pragma unroll
                for (int kc = 0; kc < 4; kc++)
                    acc = __builtin_amdgcn_mfma_f32_16x16x32_bf16(w3f[mi][kc], hf[kc], acc, 0, 0, 0);
#pragma unroll
                for (int r = 0; r < 4; r++)
                    mx[mi][r] = fmaxf(mx[mi][r], acc[r]);
            }
        }
        __syncthreads();   // s_h2 reads done before next chunk's writes / s_tmp
    }

    // partial maxes (this lane's 8 pts) -> s_tmp[lm][out_ch]
#pragma unroll
    for (int mi = 0; mi < 4; mi++)
        *(floatx4*)&s_tmp[lm * 264 + (wave * 4 + mi) * 16 + lq * 4] = mx[mi];
    __syncthreads();

    // reduce over the 16 pt-lanes; thread t = out channel
    {
        float m = s_tmp[t];
#pragma unroll
        for (int l = 1; l < 16; l++) m = fmaxf(m, s_tmp[l * 264 + t]);
        s_feat[t] = m + b3[t];
    }
    __syncthreads();

    // ---- oe: feat @ oe_w + oe_b -> out[obj, 100:200]; k split over 2 threads
    if (t < 2 * EMB) {
        const int j = t >> 1, half = t & 1;
        float acc = half ? 0.f : oeb[j];
        const unsigned short* orow = &oeT[j * 256 + half * 128];
        const float* f = &s_feat[half * 128];
        for (int c8 = 0; c8 < 16; c8++) {
            const ushort8 w8 = *(const ushort8*)&orow[c8 * 8];
            const float4 f0 = *(const float4*)&f[c8 * 8];
            const float4 f1 = *(const float4*)&f[c8 * 8 + 4];
            union { unsigned u; float fl; } cv;
            float s = 0.f;
            cv.u = (unsigned)w8[0] << 16; s += f0.x * cv.fl;
            cv.u = (unsigned)w8[1] << 16; s += f0.y * cv.fl;
            cv.u = (unsigned)w8[2] << 16; s += f0.z * cv.fl;
            cv.u = (unsigned)w8[3] << 16; s += f0.w * cv.fl;
            cv.u = (unsigned)w8[4] << 16; s += f1.x * cv.fl;
            cv.u = (unsigned)w8[5] << 16; s += f1.y * cv.fl;
            cv.u = (unsigned)w8[6] << 16; s += f1.z * cv.fl;
            cv.u = (unsigned)w8[7] << 16; s += f1.w * cv.fl;
            acc += s;
        }
        acc += __shfl_xor(acc, 1, 64);
        if (half == 0) out[obj * OUT_C + EMB + j] = acc;
    }
}

// ---------------------------------------------------------------------------
// fused kernel: blocks [0,512) sgnet (dispatched first, overlaps), rest pointnet
// ---------------------------------------------------------------------------
__global__ __launch_bounds__(256, 4) void fused_kernel(
    const float* __restrict__ pts,
    const float* __restrict__ src_feat, const float* __restrict__ ref_feat,
    const float* __restrict__ sg_b1, const float* __restrict__ sg_b2,
    const float* __restrict__ seb,
    const float* __restrict__ p_w1, const float* __restrict__ p_b1,
    const float* __restrict__ p_b2, const float* __restrict__ p_b3,
    const float* __restrict__ oeb,
    const unsigned short* __restrict__ ws,
    float* __restrict__ out)
{
    __shared__ __align__(16) unsigned char smem[SMEM_BYTES];
    const int blk = blockIdx.x;
    if (blk < 512) {
        sgnet_body(smem, blk, src_feat, ref_feat, sg_b1, sg_b2, seb, ws, out);
    } else {
        pointnet_body(smem, blk - 512, pts, p_w1, p_b1, p_b2, p_b3, ws, oeb, out);
    }
}

extern "C" void kernel_launch(void* const* d_in, const int* in_sizes, int n_in,
                              void* d_out, int out_size, void* d_ws, size_t ws_size,
                              hipStream_t stream) {
    (void)in_sizes; (void)n_in; (void)out_size; (void)ws_size;
    const float* tot_pts  = (const float*)d_in[0];
    const float* src_feat = (const float*)d_in[1];
    const float* ref_feat = (const float*)d_in[2];
    const float* sg_w1 = (const float*)d_in[6];
    const float* sg_b1 = (const float*)d_in[7];
    const float* sg_w2 = (const float*)d_in[8];
    const float* sg_b2 = (const float*)d_in[9];
    const float* se_w  = (const float*)d_in[10];
    const float* se_b  = (const float*)d_in[11];
    const float* p_w1  = (const float*)d_in[12];
    const float* p_b1  = (const float*)d_in[13];
    const float* p_w2  = (const float*)d_in[14];
    const float* p_b2  = (const float*)d_in[15];
    const float* p_w3  = (const float*)d_in[16];
    const float* p_b3  = (const float*)d_in[17];
    const float* oe_w  = (const float*)d_in[18];
    const float* oe_b  = (const float*)d_in[19];
    float* out = (float*)d_out;
    unsigned short* ws = (unsigned short*)d_ws;

    prep_kernel<<<(WS_TOT + 255) / 256, 256, 0, stream>>>(
        p_w2, p_w3, oe_w, sg_w1, sg_w2, se_w, ws);
    fused_kernel<<<512 + N_TOT, 256, 0, stream>>>(
        tot_pts, src_feat, ref_feat, sg_b1, sg_b2, se_b,
        p_w1, p_b1, p_b2, p_b3, oe_b, ws, out);
}

// Round 5
// 455.442 us; speedup vs baseline: 1.2458x; 1.2458x over previous
//
#include <hip/hip_runtime.h>
#include <hip/hip_bf16.h>
#include <math.h>

// Problem constants (fixed by the reference)
#define B_SZ   16
#define SRC_N  512
#define N_TOT  16384
#define P_PTS  128
#define FEAT   256
#define EMB    100
#define OUT_C  200   // EMB (sg) + EMB (pt)

typedef __attribute__((ext_vector_type(8))) short short8;
typedef __attribute__((ext_vector_type(8))) unsigned short ushort8;
typedef __attribute__((ext_vector_type(4))) float floatx4;

__device__ __forceinline__ unsigned short f2bf(float x) {   // RNE, scalar
    union { float f; unsigned u; } v; v.f = x;
    unsigned r = v.u + 0x7fffu + ((v.u >> 16) & 1u);
    return (unsigned short)(r >> 16);
}
// pack two f32 -> bf16x2 dword, RNE
__device__ __forceinline__ unsigned pack_rne(float a, float b) {
    union { float f; unsigned u; } x, y; x.f = a; y.f = b;
    unsigned lo = x.u + 0x7fffu + ((x.u >> 16) & 1u);
    unsigned hi = y.u + 0x7fffu + ((y.u >> 16) & 1u);
    return __builtin_amdgcn_perm(hi, lo, 0x07060302);
}
// pack two f32 -> bf16x2 dword, round-half-up (3 ops)
__device__ __forceinline__ unsigned pack_rhu(float a, float b) {
    union { float f; unsigned u; } x, y; x.f = a; y.f = b;
    return __builtin_amdgcn_perm(y.u + 0x8000u, x.u + 0x8000u, 0x07060302);
}

// d_ws layout (unsigned short elements)
#define WS_PW2T 0        // pointnet w2T [128][64]   w2T[n][k]=w2[k][n]
#define WS_PW3T 8192     // pointnet w3T [256][128]
#define WS_POET 40960    // pointnet oeT [100][256]  oeT[j][c]=oe_w[c][j]
#define WS_SGW1 66560    // sgnet w1T    [256][256]  (k natural)
#define WS_SGW2 132096   // sgnet w2Tp   [256][256]  k' permuted (perm32)
#define WS_SGSE 197632   // sgnet seTp   [112][256]  k' permuted, zero-pad j>=100
#define WS_TOT  226304

__device__ __forceinline__ int perm32(int p) {   // stored pos -> actual channel
    return 32 * (p >> 5) + 16 * (p & 1) + ((p >> 1) & 15);
}

__global__ void prep_kernel(const float* __restrict__ pw2,
                            const float* __restrict__ pw3,
                            const float* __restrict__ oew,
                            const float* __restrict__ sw1,
                            const float* __restrict__ sw2,
                            const float* __restrict__ sew,
                            unsigned short* __restrict__ ws) {
    const int o = blockIdx.x * 256 + threadIdx.x;
    if (o < WS_PW3T) {
        const int n = o >> 6, k = o & 63;
        ws[o] = f2bf(pw2[k * 128 + n]);
    } else if (o < WS_POET) {
        const int i = o - WS_PW3T;
        const int n = i >> 7, k = i & 127;
        ws[o] = f2bf(pw3[k * 256 + n]);
    } else if (o < WS_SGW1) {
        const int i = o - WS_POET;
        const int j = i >> 8, c = i & 255;
        ws[o] = f2bf(oew[c * EMB + j]);
    } else if (o < WS_SGW2) {
        const int i = o - WS_SGW1;
        const int n = i >> 8, k = i & 255;
        ws[o] = f2bf(sw1[k * 256 + n]);
    } else if (o < WS_SGSE) {
        const int i = o - WS_SGW2;
        const int n = i >> 8, kp = i & 255;
        ws[o] = f2bf(sw2[perm32(kp) * 256 + n]);
    } else if (o < WS_TOT) {
        const int i = o - WS_SGSE;
        const int n = i >> 8, kp = i & 255;
        ws[o] = (n < EMB) ? f2bf(sew[perm32(kp) * EMB + n]) : (unsigned short)0;
    }
}

#define SXS 264   // sgnet activation row stride (shorts)
#define H1S 72    // pointnet h1 row stride (shorts)
#define H2S 136   // pointnet h2 row stride (shorts)

// ---------------------------------------------------------------------------
// sgnet (MFMA). M=16 rows/block, 1024 blocks, 256 thr. Activations stored with
// perm32 channel permutation; next layer's weights carry the K-permutation.
// ---------------------------------------------------------------------------
template <bool RELU>
__device__ __forceinline__ void sg_layer(const unsigned short* s_in,
                                         unsigned short* s_out,
                                         const unsigned short* wT,
                                         const float* __restrict__ bias,
                                         int wave, int lm, int lq) {
#pragma unroll
    for (int np = 0; np < 2; np++) {
        short8 bf[2][8];
        float bv[2];
#pragma unroll
        for (int b = 0; b < 2; b++) {
            const int n = wave * 64 + (2 * np + b) * 16 + lm;
            bv[b] = bias[n];
#pragma unroll
            for (int kc = 0; kc < 8; kc++)
                bf[b][kc] = *(const short8*)&wT[n * 256 + kc * 32 + lq * 8];
        }
        short8 af[8];
#pragma unroll
        for (int kc = 0; kc < 8; kc++)
            af[kc] = *(const short8*)&s_in[lm * SXS + kc * 32 + lq * 8];
        floatx4 acc[2];
#pragma unroll
        for (int b = 0; b < 2; b++) acc[b] = {0.f, 0.f, 0.f, 0.f};
#pragma unroll
        for (int b = 0; b < 2; b++)
#pragma unroll
            for (int kc = 0; kc < 8; kc++)
                acc[b] = __builtin_amdgcn_mfma_f32_16x16x32_bf16(
                    af[kc], bf[b][kc], acc[b], 0, 0, 0);
#pragma unroll
        for (int r = 0; r < 4; r++) {
            float v0 = acc[0][r] + bv[0];
            float v1 = acc[1][r] + bv[1];
            if (RELU) { v0 = fmaxf(v0, 0.f); v1 = fmaxf(v1, 0.f); }
            *(unsigned*)&s_out[(lq * 4 + r) * SXS +
                               wave * 64 + 32 * np + 2 * lm] = pack_rne(v0, v1);
        }
    }
}

__global__ __launch_bounds__(256, 3) void sgnet_mfma_kernel(
    const float* __restrict__ src_feat, const float* __restrict__ ref_feat,
    const float* __restrict__ b1, const float* __restrict__ b2,
    const float* __restrict__ seb, const unsigned short* __restrict__ ws,
    float* __restrict__ out)
{
    __shared__ __align__(16) unsigned short s_x[16 * SXS];  // 8448 B
    __shared__ __align__(16) unsigned short s_h[16 * SXS];  // 8448 B

    const unsigned short* w1T = ws + WS_SGW1;
    const unsigned short* w2T = ws + WS_SGW2;
    const unsigned short* seT = ws + WS_SGSE;

    const int blk = blockIdx.x;
    const bool is_ref = (blk >= 512);
    const int row0 = (blk & 511) * 16;
    const float* feat = is_ref ? ref_feat : src_feat;
    const int t = threadIdx.x;
    const int wave = t >> 6, lane = t & 63, lm = lane & 15, lq = lane >> 4;

    // stage 16 rows -> bf16 LDS (natural k order): 4096 elems, 8/thread, 2 iters
#pragma unroll
    for (int i = 0; i < 2; i++) {
        const int flat = i * 2048 + t * 8;
        const int r = flat >> 8, c = flat & 255;
        const float4 a = *(const float4*)&feat[(row0 + r) * 256 + c];
        const float4 b = *(const float4*)&feat[(row0 + r) * 256 + c + 4];
        uint4 d;
        d.x = pack_rne(a.x, a.y); d.y = pack_rne(a.z, a.w);
        d.z = pack_rne(b.x, b.y); d.w = pack_rne(b.z, b.w);
        *(uint4*)&s_x[r * SXS + c] = d;
    }
    __syncthreads();

    sg_layer<true>(s_x, s_h, w1T, b1, wave, lm, lq);
    __syncthreads();
    sg_layer<false>(s_h, s_x, w2T, b2, wave, lm, lq);
    __syncthreads();

    // SE: N=112 (7 tiles), wave w owns tiles {2w, 2w+1}
#pragma unroll
    for (int s = 0; s < 2; s++) {
        const int ntt = wave * 2 + s;
        if (ntt >= 7) continue;
        const int j = ntt * 16 + lm;     // < 112
        short8 bf[8];
#pragma unroll
        for (int kc = 0; kc < 8; kc++)
            bf[kc] = *(const short8*)&seT[j * 256 + kc * 32 + lq * 8];
        const float bj = (j < EMB) ? seb[j] : 0.f;
        short8 af[8];
#pragma unroll
        for (int kc = 0; kc < 8; kc++)
            af[kc] = *(const short8*)&s_x[lm * SXS + kc * 32 + lq * 8];
        floatx4 acc = {0.f, 0.f, 0.f, 0.f};
#pragma unroll
        for (int kc = 0; kc < 8; kc++)
            acc = __builtin_amdgcn_mfma_f32_16x16x32_bf16(af[kc], bf[kc], acc, 0, 0, 0);
        if (j < EMB) {
#pragma unroll
            for (int r = 0; r < 4; r++) {
                const int grow = row0 + lq * 4 + r;
                const int pos = ((grow >> 9) << 10) + (grow & 511) + (is_ref ? 512 : 0);
                out[pos * OUT_C + j] = acc[r] + bj;
            }
        }
    }
}

// ---------------------------------------------------------------------------
// pointnet (MFMA, weights-as-A). 512 thr = 8 waves per block, 1 object/block.
// Per-wave M is halved vs round 3: h2 wave owns 16 ch (w2f 8 regs), h3 wave
// owns 32 ch (w3f 32 regs) -> ~96 unified regs, fits (512,4) cap of 128.
// LDS 35.8 KB -> 2 blocks/CU = 16 waves/CU.
// ---------------------------------------------------------------------------
__global__ __launch_bounds__(512, 4) void pointnet_mfma_kernel(
    const float* __restrict__ pts,
    const float* __restrict__ w1, const float* __restrict__ b1,
    const float* __restrict__ b2, const float* __restrict__ b3,
    const unsigned short* __restrict__ ws,
    const float* __restrict__ oeb, float* __restrict__ out)
{
    __shared__ __align__(16) unsigned short s_h1[128 * H1S];  // 18432 B
    __shared__ __align__(16) unsigned short s_h2[64 * H2S];   // 17408 B
    float* s_pts  = (float*)s_h2;               // h1 phase only (1536 B)
    float* s_tmp  = (float*)s_h1;               // [16][264] partial maxes
    float* s_feat = (float*)s_h1 + 16 * 264;    // [256] (ends 17920 <= 18432)

    const unsigned short* w2T = ws + WS_PW2T;
    const unsigned short* w3T = ws + WS_PW3T;
    const unsigned short* oeT = ws + WS_POET;

    const int obj  = blockIdx.x;
    const int t    = threadIdx.x;
    const int wave = t >> 6, lane = t & 63, lm = lane & 15, lq = lane >> 4;

    // prefetch h2 weights: wave owns 16 ch
    short8 w2f[2];
#pragma unroll
    for (int kc = 0; kc < 2; kc++)
        w2f[kc] = *(const short8*)&w2T[(wave * 16 + lm) * 64 + kc * 32 + lq * 8];
    const float4 b2v = *(const float4*)&b2[wave * 16 + lq * 4];

    // stage points
    if (t < P_PTS * 3) s_pts[t] = pts[obj * (P_PTS * 3) + t];
    __syncthreads();

    // ---- h1: relu(pts @ w1 + b1) -> s_h1[pt][64ch] bf16; 16 outputs/thread
    {
        const int k0 = (t & 7) * 8;
        float wr0[8], wr1[8], wr2[8], br[8];
#pragma unroll
        for (int j = 0; j < 8; j++) {
            wr0[j] = w1[k0 + j]; wr1[j] = w1[64 + k0 + j];
            wr2[j] = w1[128 + k0 + j]; br[j] = b1[k0 + j];
        }
#pragma unroll
        for (int i = 0; i < 2; i++) {
            const int m = (t >> 3) + i * 64;
            const float x = s_pts[m * 3 + 0];
            const float y = s_pts[m * 3 + 1];
            const float z = s_pts[m * 3 + 2];
            float v[8];
#pragma unroll
            for (int j = 0; j < 8; j++)
                v[j] = fmaxf(br[j] + x * wr0[j] + y * wr1[j] + z * wr2[j], 0.f);
            uint4 d;
            d.x = pack_rhu(v[0], v[1]); d.y = pack_rhu(v[2], v[3]);
            d.z = pack_rhu(v[4], v[5]); d.w = pack_rhu(v[6], v[7]);
            *(uint4*)&s_h1[m * H1S + k0] = d;
        }
    }

    // prefetch h3 weights: wave owns 32 ch (2 mi-tiles)
    short8 w3f[2][4];
#pragma unroll
    for (int mi = 0; mi < 2; mi++) {
        const int m = (wave * 2 + mi) * 16 + lm;
#pragma unroll
        for (int kc = 0; kc < 4; kc++)
            w3f[mi][kc] = *(const short8*)&w3T[m * 128 + kc * 32 + lq * 8];
    }

    floatx4 mx[2];
#pragma unroll
    for (int mi = 0; mi < 2; mi++) mx[mi] = {-1e30f, -1e30f, -1e30f, -1e30f};

    __syncthreads();   // s_pts dead; s_h2 writable

    // ---- chunk loop: 2 x 64 points ----
    for (int c = 0; c < 2; c++) {
        // h2: D[ch][pt] = w2T x h1^T -> packed b64 stores into s_h2[pt64][ch]
#pragma unroll
        for (int nt = 0; nt < 4; nt++) {
            short8 hf[2];
#pragma unroll
            for (int kc = 0; kc < 2; kc++)
                hf[kc] = *(const short8*)&s_h1[(c * 64 + nt * 16 + lm) * H1S + kc * 32 + lq * 8];
            floatx4 acc = {0.f, 0.f, 0.f, 0.f};
            acc = __builtin_amdgcn_mfma_f32_16x16x32_bf16(w2f[0], hf[0], acc, 0, 0, 0);
            acc = __builtin_amdgcn_mfma_f32_16x16x32_bf16(w2f[1], hf[1], acc, 0, 0, 0);
            const float v0 = fmaxf(acc[0] + b2v.x, 0.f);
            const float v1 = fmaxf(acc[1] + b2v.y, 0.f);
            const float v2 = fmaxf(acc[2] + b2v.z, 0.f);
            const float v3 = fmaxf(acc[3] + b2v.w, 0.f);
            uint2 dd;
            dd.x = pack_rhu(v0, v1);
            dd.y = pack_rhu(v2, v3);
            *(uint2*)&s_h2[(nt * 16 + lm) * H2S + wave * 16 + lq * 4] = dd;
        }
        __syncthreads();   // h2 chunk visible; (c=1) s_h1 reads done

        // h3: D[out][pt] = w3T x h2^T; running max
#pragma unroll
        for (int nt = 0; nt < 4; nt++) {
            short8 hf[4];
#pragma unroll
            for (int kc = 0; kc < 4; kc++)
                hf[kc] = *(const short8*)&s_h2[(nt * 16 + lm) * H2S + kc * 32 + lq * 8];
#pragma unroll
            for (int mi = 0; mi < 2; mi++) {
                floatx4 acc = {0.f, 0.f, 0.f, 0.f};
#pragma unroll
                for (int kc = 0; kc < 4; kc++)
                    acc = __builtin_amdgcn_mfma_f32_16x16x32_bf16(w3f[mi][kc], hf[kc], acc, 0, 0, 0);
#pragma unroll
                for (int r = 0; r < 4; r++)
                    mx[mi][r] = fmaxf(mx[mi][r], acc[r]);
            }
        }
        __syncthreads();   // s_h2 reads done before next chunk / s_tmp aliasing
    }

    // partial maxes (this lane's 8 pts) -> s_tmp[lm][out_ch]
#pragma unroll
    for (int mi = 0; mi < 2; mi++)
        *(floatx4*)&s_tmp[lm * 264 + (wave * 2 + mi) * 16 + lq * 4] = mx[mi];
    __syncthreads();

    // reduce over the 16 pt-lanes; thread t = out channel
    if (t < 256) {
        float m = s_tmp[t];
#pragma unroll
        for (int l = 1; l < 16; l++) m = fmaxf(m, s_tmp[l * 264 + t]);
        s_feat[t] = m + b3[t];
    }
    __syncthreads();

    // ---- oe: feat @ oe_w + oe_b; 4-way k-split over 400 threads ----
    if (t < 4 * EMB) {
        const int j = t >> 2, q = t & 3;
        float acc = (q == 0) ? oeb[j] : 0.f;
        const unsigned short* orow = &oeT[j * 256 + q * 64];
        const float* f = &s_feat[q * 64];
        for (int c8 = 0; c8 < 8; c8++) {
            const ushort8 w8 = *(const ushort8*)&orow[c8 * 8];
            const float4 f0 = *(const float4*)&f[c8 * 8];
            const float4 f1 = *(const float4*)&f[c8 * 8 + 4];
            union { unsigned u; float fl; } cv;
            float s = 0.f;
            cv.u = (unsigned)w8[0] << 16; s += f0.x * cv.fl;
            cv.u = (unsigned)w8[1] << 16; s += f0.y * cv.fl;
            cv.u = (unsigned)w8[2] << 16; s += f0.z * cv.fl;
            cv.u = (unsigned)w8[3] << 16; s += f0.w * cv.fl;
            cv.u = (unsigned)w8[4] << 16; s += f1.x * cv.fl;
            cv.u = (unsigned)w8[5] << 16; s += f1.y * cv.fl;
            cv.u = (unsigned)w8[6] << 16; s += f1.z * cv.fl;
            cv.u = (unsigned)w8[7] << 16; s += f1.w * cv.fl;
            acc += s;
        }
        acc += __shfl_xor(acc, 1, 64);
        acc += __shfl_xor(acc, 2, 64);
        if (q == 0) out[obj * OUT_C + EMB + j] = acc;
    }
}

extern "C" void kernel_launch(void* const* d_in, const int* in_sizes, int n_in,
                              void* d_out, int out_size, void* d_ws, size_t ws_size,
                              hipStream_t stream) {
    (void)in_sizes; (void)n_in; (void)out_size; (void)ws_size;
    const float* tot_pts  = (const float*)d_in[0];
    const float* src_feat = (const float*)d_in[1];
    const float* ref_feat = (const float*)d_in[2];
    const float* sg_w1 = (const float*)d_in[6];
    const float* sg_b1 = (const float*)d_in[7];
    const float* sg_w2 = (const float*)d_in[8];
    const float* sg_b2 = (const float*)d_in[9];
    const float* se_w  = (const float*)d_in[10];
    const float* se_b  = (const float*)d_in[11];
    const float* p_w1  = (const float*)d_in[12];
    const float* p_b1  = (const float*)d_in[13];
    const float* p_w2  = (const float*)d_in[14];
    const float* p_b2  = (const float*)d_in[15];
    const float* p_w3  = (const float*)d_in[16];
    const float* p_b3  = (const float*)d_in[17];
    const float* oe_w  = (const float*)d_in[18];
    const float* oe_b  = (const float*)d_in[19];
    float* out = (float*)d_out;
    unsigned short* ws = (unsigned short*)d_ws;

    prep_kernel<<<(WS_TOT + 255) / 256, 256, 0, stream>>>(
        p_w2, p_w3, oe_w, sg_w1, sg_w2, se_w, ws);
    sgnet_mfma_kernel<<<1024, 256, 0, stream>>>(src_feat, ref_feat, sg_b1, sg_b2,
                                                se_b, ws, out);
    pointnet_mfma_kernel<<<N_TOT, 512, 0, stream>>>(tot_pts, p_w1, p_b1,
                                                    p_b2, p_b3, ws, oe_b, out);
}

// Round 6
// 434.026 us; speedup vs baseline: 1.3073x; 1.0493x over previous
//
#include <hip/hip_runtime.h>
#include <hip/hip_bf16.h>
#include <math.h>

// Problem constants (fixed by the reference)
#define B_SZ   16
#define SRC_N  512
#define N_TOT  16384
#define P_PTS  128
#define FEAT   256
#define EMB    100
#define OUT_C  200   // EMB (sg) + EMB (pt)

typedef __attribute__((ext_vector_type(8))) short short8;
typedef __attribute__((ext_vector_type(8))) unsigned short ushort8;
typedef __attribute__((ext_vector_type(4))) float floatx4;

__device__ __forceinline__ unsigned short f2bf(float x) {   // RNE, scalar
    union { float f; unsigned u; } v; v.f = x;
    unsigned r = v.u + 0x7fffu + ((v.u >> 16) & 1u);
    return (unsigned short)(r >> 16);
}
// pack two f32 -> bf16x2 dword, RNE
__device__ __forceinline__ unsigned pack_rne(float a, float b) {
    union { float f; unsigned u; } x, y; x.f = a; y.f = b;
    unsigned lo = x.u + 0x7fffu + ((x.u >> 16) & 1u);
    unsigned hi = y.u + 0x7fffu + ((y.u >> 16) & 1u);
    return __builtin_amdgcn_perm(hi, lo, 0x07060302);
}
// pack two f32 -> bf16x2 dword, round-half-up (3 ops)
__device__ __forceinline__ unsigned pack_rhu(float a, float b) {
    union { float f; unsigned u; } x, y; x.f = a; y.f = b;
    return __builtin_amdgcn_perm(y.u + 0x8000u, x.u + 0x8000u, 0x07060302);
}

// d_ws layout (unsigned short elements)
#define WS_PW2T 0        // pointnet w2T [128][64]   w2T[n][k]=w2[k][n]
#define WS_PW3T 8192     // pointnet w3T [256][128]
#define WS_POET 40960    // pointnet oeT [100][256]  oeT[j][c]=oe_w[c][j]
#define WS_SGW1 66560    // sgnet w1T    [256][256]  (k natural)
#define WS_SGW2 132096   // sgnet w2Tp   [256][256]  k' permuted (perm32)
#define WS_SGSE 197632   // sgnet seTp   [112][256]  k' permuted, zero-pad j>=100
#define WS_TOT  226304

__device__ __forceinline__ int perm32(int p) {   // stored pos -> actual channel
    return 32 * (p >> 5) + 16 * (p & 1) + ((p >> 1) & 15);
}

__global__ void prep_kernel(const float* __restrict__ pw2,
                            const float* __restrict__ pw3,
                            const float* __restrict__ oew,
                            const float* __restrict__ sw1,
                            const float* __restrict__ sw2,
                            const float* __restrict__ sew,
                            unsigned short* __restrict__ ws) {
    const int o = blockIdx.x * 256 + threadIdx.x;
    if (o < WS_PW3T) {
        const int n = o >> 6, k = o & 63;
        ws[o] = f2bf(pw2[k * 128 + n]);
    } else if (o < WS_POET) {
        const int i = o - WS_PW3T;
        const int n = i >> 7, k = i & 127;
        ws[o] = f2bf(pw3[k * 256 + n]);
    } else if (o < WS_SGW1) {
        const int i = o - WS_POET;
        const int j = i >> 8, c = i & 255;
        ws[o] = f2bf(oew[c * EMB + j]);
    } else if (o < WS_SGW2) {
        const int i = o - WS_SGW1;
        const int n = i >> 8, k = i & 255;
        ws[o] = f2bf(sw1[k * 256 + n]);
    } else if (o < WS_SGSE) {
        const int i = o - WS_SGW2;
        const int n = i >> 8, kp = i & 255;
        ws[o] = f2bf(sw2[perm32(kp) * 256 + n]);
    } else if (o < WS_TOT) {
        const int i = o - WS_SGSE;
        const int n = i >> 8, kp = i & 255;
        ws[o] = (n < EMB) ? f2bf(sew[perm32(kp) * EMB + n]) : (unsigned short)0;
    }
}

#define SXS 264   // sgnet activation row stride (shorts)
#define H1S 72    // pointnet h1 row stride (shorts)
#define H2S 136   // pointnet h2 row stride (shorts)
#define SMEM_BYTES 53248   // max(pointnet 18432+34816, sgnet 2*8448)

// ---------------------------------------------------------------------------
// sgnet body (MFMA). M=16 rows/block. Activations stored with perm32 channel
// permutation; next layer's weights carry the matching K-permutation.
// ---------------------------------------------------------------------------
template <bool RELU>
__device__ __forceinline__ void sg_layer(const unsigned short* s_in,
                                         unsigned short* s_out,
                                         const unsigned short* wT,
                                         const float* __restrict__ bias,
                                         int wave, int lm, int lq) {
#pragma unroll
    for (int np = 0; np < 2; np++) {
        short8 bf[2][8];
        float bv[2];
#pragma unroll
        for (int b = 0; b < 2; b++) {
            const int n = wave * 64 + (2 * np + b) * 16 + lm;
            bv[b] = bias[n];
#pragma unroll
            for (int kc = 0; kc < 8; kc++)
                bf[b][kc] = *(const short8*)&wT[n * 256 + kc * 32 + lq * 8];
        }
        short8 af[8];
#pragma unroll
        for (int kc = 0; kc < 8; kc++)
            af[kc] = *(const short8*)&s_in[lm * SXS + kc * 32 + lq * 8];
        floatx4 acc[2];
#pragma unroll
        for (int b = 0; b < 2; b++) acc[b] = {0.f, 0.f, 0.f, 0.f};
#pragma unroll
        for (int b = 0; b < 2; b++)
#pragma unroll
            for (int kc = 0; kc < 8; kc++)
                acc[b] = __builtin_amdgcn_mfma_f32_16x16x32_bf16(
                    af[kc], bf[b][kc], acc[b], 0, 0, 0);
#pragma unroll
        for (int r = 0; r < 4; r++) {
            float v0 = acc[0][r] + bv[0];
            float v1 = acc[1][r] + bv[1];
            if (RELU) { v0 = fmaxf(v0, 0.f); v1 = fmaxf(v1, 0.f); }
            *(unsigned*)&s_out[(lq * 4 + r) * SXS +
                               wave * 64 + 32 * np + 2 * lm] = pack_rne(v0, v1);
        }
    }
}

__device__ void sgnet_body(unsigned char* smem, int blk,
                           const float* __restrict__ src_feat,
                           const float* __restrict__ ref_feat,
                           const float* __restrict__ b1,
                           const float* __restrict__ b2,
                           const float* __restrict__ seb,
                           const unsigned short* __restrict__ ws,
                           float* __restrict__ out)
{
    unsigned short* s_x = (unsigned short*)smem;        // 16*SXS = 8448 B
    unsigned short* s_h = s_x + 16 * SXS;               // 8448 B

    const unsigned short* w1T = ws + WS_SGW1;
    const unsigned short* w2T = ws + WS_SGW2;
    const unsigned short* seT = ws + WS_SGSE;

    const bool is_ref = (blk >= 512);
    const int row0 = (blk & 511) * 16;
    const float* feat = is_ref ? ref_feat : src_feat;
    const int t = threadIdx.x;
    const int wave = t >> 6, lane = t & 63, lm = lane & 15, lq = lane >> 4;

    // stage 16 rows -> bf16 LDS (natural k order)
#pragma unroll
    for (int i = 0; i < 2; i++) {
        const int flat = i * 2048 + t * 8;
        const int r = flat >> 8, c = flat & 255;
        const float4 a = *(const float4*)&feat[(row0 + r) * 256 + c];
        const float4 b = *(const float4*)&feat[(row0 + r) * 256 + c + 4];
        uint4 d;
        d.x = pack_rne(a.x, a.y); d.y = pack_rne(a.z, a.w);
        d.z = pack_rne(b.x, b.y); d.w = pack_rne(b.z, b.w);
        *(uint4*)&s_x[r * SXS + c] = d;
    }
    __syncthreads();

    sg_layer<true>(s_x, s_h, w1T, b1, wave, lm, lq);
    __syncthreads();
    sg_layer<false>(s_h, s_x, w2T, b2, wave, lm, lq);
    __syncthreads();

    // SE: N=112 (7 tiles), wave w owns tiles {2w, 2w+1}
#pragma unroll
    for (int s = 0; s < 2; s++) {
        const int ntt = wave * 2 + s;
        if (ntt >= 7) continue;
        const int j = ntt * 16 + lm;     // < 112
        short8 bf[8];
#pragma unroll
        for (int kc = 0; kc < 8; kc++)
            bf[kc] = *(const short8*)&seT[j * 256 + kc * 32 + lq * 8];
        const float bj = (j < EMB) ? seb[j] : 0.f;
        short8 af[8];
#pragma unroll
        for (int kc = 0; kc < 8; kc++)
            af[kc] = *(const short8*)&s_x[lm * SXS + kc * 32 + lq * 8];
        floatx4 acc = {0.f, 0.f, 0.f, 0.f};
#pragma unroll
        for (int kc = 0; kc < 8; kc++)
            acc = __builtin_amdgcn_mfma_f32_16x16x32_bf16(af[kc], bf[kc], acc, 0, 0, 0);
        if (j < EMB) {
#pragma unroll
            for (int r = 0; r < 4; r++) {
                const int grow = row0 + lq * 4 + r;
                const int pos = ((grow >> 9) << 10) + (grow & 511) + (is_ref ? 512 : 0);
                out[pos * OUT_C + j] = acc[r] + bj;
            }
        }
    }
}

// ---------------------------------------------------------------------------
// pointnet body (MFMA, weights-as-A) — round-3 shape: 256 thr / 4 waves,
// full 128-pt s_h2, wave owns 32 h2-ch and 64 h3-ch (max operand reuse).
// ---------------------------------------------------------------------------
__device__ void pointnet_body(unsigned char* smem, int obj,
                              const float* __restrict__ pts,
                              const float* __restrict__ w1,
                              const float* __restrict__ b1,
                              const float* __restrict__ b2,
                              const float* __restrict__ b3,
                              const unsigned short* __restrict__ ws,
                              const float* __restrict__ oeb,
                              float* __restrict__ out)
{
    unsigned short* s_h1 = (unsigned short*)smem;                 // 128*H1S = 18432 B
    unsigned short* s_h2 = (unsigned short*)(smem + 18432);       // 128*H2S = 34816 B
    float* s_pts  = (float*)s_h2;               // h1 phase only (1536 B)
    float* s_tmp  = (float*)s_h1;               // [16][264] partial maxes
    float* s_feat = (float*)s_h1 + 16 * 264;    // [256] (ends 17920 <= 18432)

    const unsigned short* w2T = ws + WS_PW2T;
    const unsigned short* w3T = ws + WS_PW3T;
    const unsigned short* oeT = ws + WS_POET;

    const int t = threadIdx.x;
    const int wave = t >> 6, lane = t & 63, lm = lane & 15, lq = lane >> 4;

    // prefetch h2 weights (A-frags) + bias vectors
    short8 w2f[2][2];
    float4 b2v[2];
#pragma unroll
    for (int mi = 0; mi < 2; mi++) {
        const int m = (wave * 2 + mi) * 16 + lm;
#pragma unroll
        for (int kc = 0; kc < 2; kc++)
            w2f[mi][kc] = *(const short8*)&w2T[m * 64 + kc * 32 + lq * 8];
        b2v[mi] = *(const float4*)&b2[(wave * 2 + mi) * 16 + lq * 4];
    }

    // stage points
    for (int i = t; i < P_PTS * 3; i += 256)
        s_pts[i] = pts[obj * (P_PTS * 3) + i];
    __syncthreads();

    // ---- h1: relu(pts @ w1 + b1) -> s_h1[pt][64ch] bf16 ----
    {
        const int k0 = (t & 7) * 8;
        float wr0[8], wr1[8], wr2[8], br[8];
#pragma unroll
        for (int j = 0; j < 8; j++) {
            wr0[j] = w1[k0 + j]; wr1[j] = w1[64 + k0 + j];
            wr2[j] = w1[128 + k0 + j]; br[j] = b1[k0 + j];
        }
#pragma unroll
        for (int i = 0; i < 4; i++) {
            const int m = (t >> 3) + i * 32;
            const float x = s_pts[m * 3 + 0];
            const float y = s_pts[m * 3 + 1];
            const float z = s_pts[m * 3 + 2];
            float v[8];
#pragma unroll
            for (int j = 0; j < 8; j++)
                v[j] = fmaxf(br[j] + x * wr0[j] + y * wr1[j] + z * wr2[j], 0.f);
            uint4 d;
            d.x = pack_rhu(v[0], v[1]); d.y = pack_rhu(v[2], v[3]);
            d.z = pack_rhu(v[4], v[5]); d.w = pack_rhu(v[6], v[7]);
            *(uint4*)&s_h1[m * H1S + k0] = d;
        }
    }

    // prefetch h3 weights (A-frags) while h1 drains
    short8 w3f[4][4];
#pragma unroll
    for (int mi = 0; mi < 4; mi++) {
        const int m = (wave * 4 + mi) * 16 + lm;
#pragma unroll
        for (int kc = 0; kc < 4; kc++)
            w3f[mi][kc] = *(const short8*)&w3T[m * 128 + kc * 32 + lq * 8];
    }
    __syncthreads();   // s_pts dead; s_h2 writable

    // ---- h2: D[ch][pt] = w2T x h1^T; packed b64 stores -> s_h2[pt][ch] ----
#pragma unroll
    for (int nt = 0; nt < 8; nt++) {
        short8 hf[2];
#pragma unroll
        for (int kc = 0; kc < 2; kc++)
            hf[kc] = *(const short8*)&s_h1[(nt * 16 + lm) * H1S + kc * 32 + lq * 8];
#pragma unroll
        for (int mi = 0; mi < 2; mi++) {
            floatx4 acc = {0.f, 0.f, 0.f, 0.f};
            acc = __builtin_amdgcn_mfma_f32_16x16x32_bf16(w2f[mi][0], hf[0], acc, 0, 0, 0);
            acc = __builtin_amdgcn_mfma_f32_16x16x32_bf16(w2f[mi][1], hf[1], acc, 0, 0, 0);
            const float v0 = fmaxf(acc[0] + b2v[mi].x, 0.f);
            const float v1 = fmaxf(acc[1] + b2v[mi].y, 0.f);
            const float v2 = fmaxf(acc[2] + b2v[mi].z, 0.f);
            const float v3 = fmaxf(acc[3] + b2v[mi].w, 0.f);
            uint2 dd;
            dd.x = pack_rhu(v0, v1);
            dd.y = pack_rhu(v2, v3);
            *(uint2*)&s_h2[(nt * 16 + lm) * H2S + (wave * 2 + mi) * 16 + lq * 4] = dd;
        }
    }
    __syncthreads();   // s_h1 dead -> s_tmp/s_feat region writable

    // ---- h3: D[out][pt] = w3T x h2^T; max over pts ----
    {
        floatx4 mx[4];
#pragma unroll
        for (int mi = 0; mi < 4; mi++) mx[mi] = {-1e30f, -1e30f, -1e30f, -1e30f};
#pragma unroll
        for (int nt = 0; nt < 8; nt++) {
            short8 hf[4];
#pragma unroll
            for (int kc = 0; kc < 4; kc++)
                hf[kc] = *(const short8*)&s_h2[(nt * 16 + lm) * H2S + kc * 32 + lq * 8];
#pragma unroll
            for (int mi = 0; mi < 4; mi++) {
                floatx4 acc = {0.f, 0.f, 0.f, 0.f};
#pragma unroll
                for (int kc = 0; kc < 4; kc++)
                    acc = __builtin_amdgcn_mfma_f32_16x16x32_bf16(w3f[mi][kc], hf[kc], acc, 0, 0, 0);
#pragma unroll
                for (int r = 0; r < 4; r++)
                    mx[mi][r] = fmaxf(mx[mi][r], acc[r]);
            }
        }
        // partial maxes (max over this lane's 8 pts) -> s_tmp[lm][out_ch]
#pragma unroll
        for (int mi = 0; mi < 4; mi++)
            *(floatx4*)&s_tmp[lm * 264 + (wave * 4 + mi) * 16 + lq * 4] = mx[mi];
    }
    __syncthreads();

    // reduce over the 16 pt-lanes; thread t = out channel
    {
        float m = s_tmp[t];
#pragma unroll
        for (int l = 1; l < 16; l++) m = fmaxf(m, s_tmp[l * 264 + t]);
        s_feat[t] = m + b3[t];
    }
    __syncthreads();

    // ---- oe: feat @ oe_w + oe_b -> out[obj, 100:200]; k split over 2 threads
    if (t < 2 * EMB) {
        const int j = t >> 1, half = t & 1;
        float acc = half ? 0.f : oeb[j];
        const unsigned short* orow = &oeT[j * 256 + half * 128];
        const float* f = &s_feat[half * 128];
        for (int c8 = 0; c8 < 16; c8++) {
            const ushort8 w8 = *(const ushort8*)&orow[c8 * 8];
            const float4 f0 = *(const float4*)&f[c8 * 8];
            const float4 f1 = *(const float4*)&f[c8 * 8 + 4];
            union { unsigned u; float fl; } cv;
            float s = 0.f;
            cv.u = (unsigned)w8[0] << 16; s += f0.x * cv.fl;
            cv.u = (unsigned)w8[1] << 16; s += f0.y * cv.fl;
            cv.u = (unsigned)w8[2] << 16; s += f0.z * cv.fl;
            cv.u = (unsigned)w8[3] << 16; s += f0.w * cv.fl;
            cv.u = (unsigned)w8[4] << 16; s += f1.x * cv.fl;
            cv.u = (unsigned)w8[5] << 16; s += f1.y * cv.fl;
            cv.u = (unsigned)w8[6] << 16; s += f1.z * cv.fl;
            cv.u = (unsigned)w8[7] << 16; s += f1.w * cv.fl;
            acc += s;
        }
        acc += __shfl_xor(acc, 1, 64);
        if (half == 0) out[obj * OUT_C + EMB + j] = acc;
    }
}

// ---------------------------------------------------------------------------
// fused kernel at (256,3): VGPR cap ~168 fits both bodies (round-4's failure
// was the 128-reg cap at (256,4)). Blocks [0,1024) sgnet, rest pointnet.
// ---------------------------------------------------------------------------
__global__ __launch_bounds__(256, 3) void fused_kernel(
    const float* __restrict__ pts,
    const float* __restrict__ src_feat, const float* __restrict__ ref_feat,
    const float* __restrict__ sg_b1, const float* __restrict__ sg_b2,
    const float* __restrict__ seb,
    const float* __restrict__ p_w1, const float* __restrict__ p_b1,
    const float* __restrict__ p_b2, const float* __restrict__ p_b3,
    const float* __restrict__ oeb,
    const unsigned short* __restrict__ ws,
    float* __restrict__ out)
{
    __shared__ __align__(16) unsigned char smem[SMEM_BYTES];
    const int blk = blockIdx.x;
    if (blk < 1024) {
        sgnet_body(smem, blk, src_feat, ref_feat, sg_b1, sg_b2, seb, ws, out);
    } else {
        pointnet_body(smem, blk - 1024, pts, p_w1, p_b1, p_b2, p_b3, ws, oeb, out);
    }
}

extern "C" void kernel_launch(void* const* d_in, const int* in_sizes, int n_in,
                              void* d_out, int out_size, void* d_ws, size_t ws_size,
                              hipStream_t stream) {
    (void)in_sizes; (void)n_in; (void)out_size; (void)ws_size;
    const float* tot_pts  = (const float*)d_in[0];
    const float* src_feat = (const float*)d_in[1];
    const float* ref_feat = (const float*)d_in[2];
    const float* sg_w1 = (const float*)d_in[6];
    const float* sg_b1 = (const float*)d_in[7];
    const float* sg_w2 = (const float*)d_in[8];
    const float* sg_b2 = (const float*)d_in[9];
    const float* se_w  = (const float*)d_in[10];
    const float* se_b  = (const float*)d_in[11];
    const float* p_w1  = (const float*)d_in[12];
    const float* p_b1  = (const float*)d_in[13];
    const float* p_w2  = (const float*)d_in[14];
    const float* p_b2  = (const float*)d_in[15];
    const float* p_w3  = (const float*)d_in[16];
    const float* p_b3  = (const float*)d_in[17];
    const float* oe_w  = (const float*)d_in[18];
    const float* oe_b  = (const float*)d_in[19];
    float* out = (float*)d_out;
    unsigned short* ws = (unsigned short*)d_ws;

    prep_kernel<<<(WS_TOT + 255) / 256, 256, 0, stream>>>(
        p_w2, p_w3, oe_w, sg_w1, sg_w2, se_w, ws);
    fused_kernel<<<1024 + N_TOT, 256, 0, stream>>>(
        tot_pts, src_feat, ref_feat, sg_b1, sg_b2, se_b,
        p_w1, p_b1, p_b2, p_b3, oe_b, ws, out);
}

// Round 7
// 429.045 us; speedup vs baseline: 1.3224x; 1.0116x over previous
//
#include <hip/hip_runtime.h>
#include <hip/hip_bf16.h>
#include <math.h>

// Problem constants (fixed by the reference)
#define B_SZ   16
#define SRC_N  512
#define N_TOT  16384
#define P_PTS  128
#define FEAT   256
#define EMB    100
#define OUT_C  200   // EMB (sg) + EMB (pt)

typedef __attribute__((ext_vector_type(8))) short short8;
typedef __attribute__((ext_vector_type(8))) unsigned short ushort8;
typedef __attribute__((ext_vector_type(4))) float floatx4;

__device__ __forceinline__ unsigned short f2bf(float x) {   // RNE, scalar
    union { float f; unsigned u; } v; v.f = x;
    unsigned r = v.u + 0x7fffu + ((v.u >> 16) & 1u);
    return (unsigned short)(r >> 16);
}
// pack two f32 -> bf16x2 dword, RNE
__device__ __forceinline__ unsigned pack_rne(float a, float b) {
    union { float f; unsigned u; } x, y; x.f = a; y.f = b;
    unsigned lo = x.u + 0x7fffu + ((x.u >> 16) & 1u);
    unsigned hi = y.u + 0x7fffu + ((y.u >> 16) & 1u);
    return __builtin_amdgcn_perm(hi, lo, 0x07060302);
}
// pack two f32 -> bf16x2 dword, round-half-up (3 ops)
__device__ __forceinline__ unsigned pack_rhu(float a, float b) {
    union { float f; unsigned u; } x, y; x.f = a; y.f = b;
    return __builtin_amdgcn_perm(y.u + 0x8000u, x.u + 0x8000u, 0x07060302);
}

// d_ws layout (unsigned short elements)
#define WS_PW2T 0        // pointnet w2T [128][64]   w2T[n][k]=w2[k][n]
#define WS_PW3T 8192     // pointnet w3T [256][128]
#define WS_POET 40960    // pointnet oeT [100][256]  oeT[j][c]=oe_w[c][j]
#define WS_SGW1 66560    // sgnet w1T    [256][256]  (k natural)
#define WS_SGW2 132096   // sgnet w2Tp   [256][256]  k' permuted (perm32)
#define WS_SGSE 197632   // sgnet seTp   [112][256]  k' permuted, zero-pad j>=100
#define WS_TOT  226304

__device__ __forceinline__ int perm32(int p) {   // stored pos -> actual channel
    return 32 * (p >> 5) + 16 * (p & 1) + ((p >> 1) & 15);
}

__global__ void prep_kernel(const float* __restrict__ pw2,
                            const float* __restrict__ pw3,
                            const float* __restrict__ oew,
                            const float* __restrict__ sw1,
                            const float* __restrict__ sw2,
                            const float* __restrict__ sew,
                            unsigned short* __restrict__ ws) {
    const int o = blockIdx.x * 256 + threadIdx.x;
    if (o < WS_PW3T) {
        const int n = o >> 6, k = o & 63;
        ws[o] = f2bf(pw2[k * 128 + n]);
    } else if (o < WS_POET) {
        const int i = o - WS_PW3T;
        const int n = i >> 7, k = i & 127;
        ws[o] = f2bf(pw3[k * 256 + n]);
    } else if (o < WS_SGW1) {
        const int i = o - WS_POET;
        const int j = i >> 8, c = i & 255;
        ws[o] = f2bf(oew[c * EMB + j]);
    } else if (o < WS_SGW2) {
        const int i = o - WS_SGW1;
        const int n = i >> 8, k = i & 255;
        ws[o] = f2bf(sw1[k * 256 + n]);
    } else if (o < WS_SGSE) {
        const int i = o - WS_SGW2;
        const int n = i >> 8, kp = i & 255;
        ws[o] = f2bf(sw2[perm32(kp) * 256 + n]);
    } else if (o < WS_TOT) {
        const int i = o - WS_SGSE;
        const int n = i >> 8, kp = i & 255;
        ws[o] = (n < EMB) ? f2bf(sew[perm32(kp) * EMB + n]) : (unsigned short)0;
    }
}

#define SXS 264   // sgnet activation row stride (shorts)
#define H1S 72    // pointnet h1 row stride (shorts)
// pointnet s_h2: 64 pts x 128 ch, unpadded, 16B-group XOR swizzle (g ^= pt&7)
#define SMEM_BYTES 34816   // max(pointnet 18432+16384, sgnet 2*8448=16896)

// ---------------------------------------------------------------------------
// sgnet body (MFMA). M=16 rows/block. Activations stored with perm32 channel
// permutation; next layer's weights carry the matching K-permutation.
// ---------------------------------------------------------------------------
template <bool RELU>
__device__ __forceinline__ void sg_layer(const unsigned short* s_in,
                                         unsigned short* s_out,
                                         const unsigned short* wT,
                                         const float* __restrict__ bias,
                                         int wave, int lm, int lq) {
#pragma unroll
    for (int np = 0; np < 2; np++) {
        short8 bf[2][8];
        float bv[2];
#pragma unroll
        for (int b = 0; b < 2; b++) {
            const int n = wave * 64 + (2 * np + b) * 16 + lm;
            bv[b] = bias[n];
#pragma unroll
            for (int kc = 0; kc < 8; kc++)
                bf[b][kc] = *(const short8*)&wT[n * 256 + kc * 32 + lq * 8];
        }
        short8 af[8];
#pragma unroll
        for (int kc = 0; kc < 8; kc++)
            af[kc] = *(const short8*)&s_in[lm * SXS + kc * 32 + lq * 8];
        floatx4 acc[2];
#pragma unroll
        for (int b = 0; b < 2; b++) acc[b] = {0.f, 0.f, 0.f, 0.f};
#pragma unroll
        for (int b = 0; b < 2; b++)
#pragma unroll
            for (int kc = 0; kc < 8; kc++)
                acc[b] = __builtin_amdgcn_mfma_f32_16x16x32_bf16(
                    af[kc], bf[b][kc], acc[b], 0, 0, 0);
#pragma unroll
        for (int r = 0; r < 4; r++) {
            float v0 = acc[0][r] + bv[0];
            float v1 = acc[1][r] + bv[1];
            if (RELU) { v0 = fmaxf(v0, 0.f); v1 = fmaxf(v1, 0.f); }
            *(unsigned*)&s_out[(lq * 4 + r) * SXS +
                               wave * 64 + 32 * np + 2 * lm] = pack_rne(v0, v1);
        }
    }
}

__device__ void sgnet_body(unsigned char* smem, int blk,
                           const float* __restrict__ src_feat,
                           const float* __restrict__ ref_feat,
                           const float* __restrict__ b1,
                           const float* __restrict__ b2,
                           const float* __restrict__ seb,
                           const unsigned short* __restrict__ ws,
                           float* __restrict__ out)
{
    unsigned short* s_x = (unsigned short*)smem;        // 16*SXS = 8448 B
    unsigned short* s_h = s_x + 16 * SXS;               // 8448 B

    const unsigned short* w1T = ws + WS_SGW1;
    const unsigned short* w2T = ws + WS_SGW2;
    const unsigned short* seT = ws + WS_SGSE;

    const bool is_ref = (blk >= 512);
    const int row0 = (blk & 511) * 16;
    const float* feat = is_ref ? ref_feat : src_feat;
    const int t = threadIdx.x;
    const int wave = t >> 6, lane = t & 63, lm = lane & 15, lq = lane >> 4;

    // stage 16 rows -> bf16 LDS (natural k order)
#pragma unroll
    for (int i = 0; i < 2; i++) {
        const int flat = i * 2048 + t * 8;
        const int r = flat >> 8, c = flat & 255;
        const float4 a = *(const float4*)&feat[(row0 + r) * 256 + c];
        const float4 b = *(const float4*)&feat[(row0 + r) * 256 + c + 4];
        uint4 d;
        d.x = pack_rne(a.x, a.y); d.y = pack_rne(a.z, a.w);
        d.z = pack_rne(b.x, b.y); d.w = pack_rne(b.z, b.w);
        *(uint4*)&s_x[r * SXS + c] = d;
    }
    __syncthreads();

    sg_layer<true>(s_x, s_h, w1T, b1, wave, lm, lq);
    __syncthreads();
    sg_layer<false>(s_h, s_x, w2T, b2, wave, lm, lq);
    __syncthreads();

    // SE: N=112 (7 tiles), wave w owns tiles {2w, 2w+1}
#pragma unroll
    for (int s = 0; s < 2; s++) {
        const int ntt = wave * 2 + s;
        if (ntt >= 7) continue;
        const int j = ntt * 16 + lm;     // < 112
        short8 bf[8];
#pragma unroll
        for (int kc = 0; kc < 8; kc++)
            bf[kc] = *(const short8*)&seT[j * 256 + kc * 32 + lq * 8];
        const float bj = (j < EMB) ? seb[j] : 0.f;
        short8 af[8];
#pragma unroll
        for (int kc = 0; kc < 8; kc++)
            af[kc] = *(const short8*)&s_x[lm * SXS + kc * 32 + lq * 8];
        floatx4 acc = {0.f, 0.f, 0.f, 0.f};
#pragma unroll
        for (int kc = 0; kc < 8; kc++)
            acc = __builtin_amdgcn_mfma_f32_16x16x32_bf16(af[kc], bf[kc], acc, 0, 0, 0);
        if (j < EMB) {
#pragma unroll
            for (int r = 0; r < 4; r++) {
                const int grow = row0 + lq * 4 + r;
                const int pos = ((grow >> 9) << 10) + (grow & 511) + (is_ref ? 512 : 0);
                out[pos * OUT_C + j] = acc[r] + bj;
            }
        }
    }
}

// ---------------------------------------------------------------------------
// pointnet body (MFMA, weights-as-A). 256 thr / 4 waves. Wave owns 32 h2-ch
// and 64 h3-ch (max operand reuse). s_h2 chunked to 64 pts, unpadded 256 B
// rows with 16B-group XOR swizzle (group ^= pt&7) -> 2-way (free) LDS access
// on both the h2 stores and h3 reads; LDS total 34.8 KB -> 4 blocks/CU.
// ---------------------------------------------------------------------------
__device__ void pointnet_body(unsigned char* smem, int obj,
                              const float* __restrict__ pts,
                              const float* __restrict__ w1,
                              const float* __restrict__ b1,
                              const float* __restrict__ b2,
                              const float* __restrict__ b3,
                              const unsigned short* __restrict__ ws,
                              const float* __restrict__ oeb,
                              float* __restrict__ out)
{
    unsigned short* s_h1 = (unsigned short*)smem;                 // 128*H1S = 18432 B
    unsigned short* s_h2 = (unsigned short*)(smem + 18432);       // 64*128*2 = 16384 B
    float* s_pts  = (float*)s_h2;               // h1 phase only (1536 B)
    float* s_tmp  = (float*)s_h1;               // [16][264] partial maxes
    float* s_feat = (float*)s_h1 + 16 * 264;    // [256] (ends 17920 <= 18432)

    const unsigned short* w2T = ws + WS_PW2T;
    const unsigned short* w3T = ws + WS_PW3T;
    const unsigned short* oeT = ws + WS_POET;

    const int t = threadIdx.x;
    const int wave = t >> 6, lane = t & 63, lm = lane & 15, lq = lane >> 4;

    // prefetch h2 weights (A-frags) + bias vectors
    short8 w2f[2][2];
    float4 b2v[2];
#pragma unroll
    for (int mi = 0; mi < 2; mi++) {
        const int m = (wave * 2 + mi) * 16 + lm;
#pragma unroll
        for (int kc = 0; kc < 2; kc++)
            w2f[mi][kc] = *(const short8*)&w2T[m * 64 + kc * 32 + lq * 8];
        b2v[mi] = *(const float4*)&b2[(wave * 2 + mi) * 16 + lq * 4];
    }

    // stage points
    for (int i = t; i < P_PTS * 3; i += 256)
        s_pts[i] = pts[obj * (P_PTS * 3) + i];
    __syncthreads();

    // ---- h1: relu(pts @ w1 + b1) -> s_h1[pt][64ch] bf16 ----
    {
        const int k0 = (t & 7) * 8;
        float wr0[8], wr1[8], wr2[8], br[8];
#pragma unroll
        for (int j = 0; j < 8; j++) {
            wr0[j] = w1[k0 + j]; wr1[j] = w1[64 + k0 + j];
            wr2[j] = w1[128 + k0 + j]; br[j] = b1[k0 + j];
        }
#pragma unroll
        for (int i = 0; i < 4; i++) {
            const int m = (t >> 3) + i * 32;
            const float x = s_pts[m * 3 + 0];
            const float y = s_pts[m * 3 + 1];
            const float z = s_pts[m * 3 + 2];
            float v[8];
#pragma unroll
            for (int j = 0; j < 8; j++)
                v[j] = fmaxf(br[j] + x * wr0[j] + y * wr1[j] + z * wr2[j], 0.f);
            uint4 d;
            d.x = pack_rhu(v[0], v[1]); d.y = pack_rhu(v[2], v[3]);
            d.z = pack_rhu(v[4], v[5]); d.w = pack_rhu(v[6], v[7]);
            *(uint4*)&s_h1[m * H1S + k0] = d;
        }
    }

    // prefetch h3 weights (A-frags) while h1 drains
    short8 w3f[4][4];
#pragma unroll
    for (int mi = 0; mi < 4; mi++) {
        const int m = (wave * 4 + mi) * 16 + lm;
#pragma unroll
        for (int kc = 0; kc < 4; kc++)
            w3f[mi][kc] = *(const short8*)&w3T[m * 128 + kc * 32 + lq * 8];
    }

    floatx4 mx[4];
#pragma unroll
    for (int mi = 0; mi < 4; mi++) mx[mi] = {-1e30f, -1e30f, -1e30f, -1e30f};

    __syncthreads();   // s_pts dead; s_h2 writable

    // ---- chunk loop: 2 x 64 points ----
    for (int c = 0; c < 2; c++) {
        // h2: D[ch][pt] = w2T x h1^T -> swizzled b64 stores into s_h2
#pragma unroll
        for (int nt = 0; nt < 4; nt++) {
            const int p = nt * 16 + lm;        // local pt in chunk
            short8 hf[2];
#pragma unroll
            for (int kc = 0; kc < 2; kc++)
                hf[kc] = *(const short8*)&s_h1[(c * 64 + p) * H1S + kc * 32 + lq * 8];
#pragma unroll
            for (int mi = 0; mi < 2; mi++) {
                floatx4 acc = {0.f, 0.f, 0.f, 0.f};
                acc = __builtin_amdgcn_mfma_f32_16x16x32_bf16(w2f[mi][0], hf[0], acc, 0, 0, 0);
                acc = __builtin_amdgcn_mfma_f32_16x16x32_bf16(w2f[mi][1], hf[1], acc, 0, 0, 0);
                const float v0 = fmaxf(acc[0] + b2v[mi].x, 0.f);
                const float v1 = fmaxf(acc[1] + b2v[mi].y, 0.f);
                const float v2 = fmaxf(acc[2] + b2v[mi].z, 0.f);
                const float v3 = fmaxf(acc[3] + b2v[mi].w, 0.f);
                uint2 dd;
                dd.x = pack_rhu(v0, v1);
                dd.y = pack_rhu(v2, v3);
                // ch = (wave*2+mi)*16 + lq*4 ; 16B group g = ch>>3, swizzle g^=p&7
                const int g = (wave * 2 + mi) * 2 + (lq >> 1);
                *(uint2*)&s_h2[p * 128 + ((g ^ (p & 7)) << 3) + (lq & 1) * 4] = dd;
            }
        }
        __syncthreads();   // h2 chunk visible; (c=1) prior s_h2 reads done

        // h3: D[out][pt] = w3T x h2^T; running max
#pragma unroll
        for (int nt = 0; nt < 4; nt++) {
            const int p = nt * 16 + lm;
            short8 hf[4];
#pragma unroll
            for (int kc = 0; kc < 4; kc++) {
                const int g = kc * 4 + lq;     // ch group kc*32+lq*8 -> g
                hf[kc] = *(const short8*)&s_h2[p * 128 + ((g ^ (p & 7)) << 3)];
            }
#pragma unroll
            for (int mi = 0; mi < 4; mi++) {
                floatx4 acc = {0.f, 0.f, 0.f, 0.f};
#pragma unroll
                for (int kc = 0; kc < 4; kc++)
                    acc = __builtin_amdgcn_mfma_f32_16x16x32_bf16(w3f[mi][kc], hf[kc], acc, 0, 0, 0);
#pragma unroll
                for (int r = 0; r < 4; r++)
                    mx[mi][r] = fmaxf(mx[mi][r], acc[r]);
            }
        }
        __syncthreads();   // s_h2 reads done before next chunk / s_tmp aliasing
    }

    // partial maxes (this lane's 8 pts) -> s_tmp[lm][out_ch]
#pragma unroll
    for (int mi = 0; mi < 4; mi++)
        *(floatx4*)&s_tmp[lm * 264 + (wave * 4 + mi) * 16 + lq * 4] = mx[mi];
    __syncthreads();

    // reduce over the 16 pt-lanes; thread t = out channel
    {
        float m = s_tmp[t];
#pragma unroll
        for (int l = 1; l < 16; l++) m = fmaxf(m, s_tmp[l * 264 + t]);
        s_feat[t] = m + b3[t];
    }
    __syncthreads();

    // ---- oe: feat @ oe_w + oe_b -> out[obj, 100:200]; k split over 2 threads
    if (t < 2 * EMB) {
        const int j = t >> 1, half = t & 1;
        float acc = half ? 0.f : oeb[j];
        const unsigned short* orow = &oeT[j * 256 + half * 128];
        const float* f = &s_feat[half * 128];
        for (int c8 = 0; c8 < 16; c8++) {
            const ushort8 w8 = *(const ushort8*)&orow[c8 * 8];
            const float4 f0 = *(const float4*)&f[c8 * 8];
            const float4 f1 = *(const float4*)&f[c8 * 8 + 4];
            union { unsigned u; float fl; } cv;
            float s = 0.f;
            cv.u = (unsigned)w8[0] << 16; s += f0.x * cv.fl;
            cv.u = (unsigned)w8[1] << 16; s += f0.y * cv.fl;
            cv.u = (unsigned)w8[2] << 16; s += f0.z * cv.fl;
            cv.u = (unsigned)w8[3] << 16; s += f0.w * cv.fl;
            cv.u = (unsigned)w8[4] << 16; s += f1.x * cv.fl;
            cv.u = (unsigned)w8[5] << 16; s += f1.y * cv.fl;
            cv.u = (unsigned)w8[6] << 16; s += f1.z * cv.fl;
            cv.u = (unsigned)w8[7] << 16; s += f1.w * cv.fl;
            acc += s;
        }
        acc += __shfl_xor(acc, 1, 64);
        if (half == 0) out[obj * OUT_C + EMB + j] = acc;
    }
}

// ---------------------------------------------------------------------------
// fused kernel at (256,3): blocks [0,1024) sgnet, rest pointnet. LDS 34.8 KB
// -> 4 blocks/CU (VGPR 68 doesn't cap; launch_bounds is a floor, not ceiling).
// ---------------------------------------------------------------------------
__global__ __launch_bounds__(256, 3) void fused_kernel(
    const float* __restrict__ pts,
    const float* __restrict__ src_feat, const float* __restrict__ ref_feat,
    const float* __restrict__ sg_b1, const float* __restrict__ sg_b2,
    const float* __restrict__ seb,
    const float* __restrict__ p_w1, const float* __restrict__ p_b1,
    const float* __restrict__ p_b2, const float* __restrict__ p_b3,
    const float* __restrict__ oeb,
    const unsigned short* __restrict__ ws,
    float* __restrict__ out)
{
    __shared__ __align__(16) unsigned char smem[SMEM_BYTES];
    const int blk = blockIdx.x;
    if (blk < 1024) {
        sgnet_body(smem, blk, src_feat, ref_feat, sg_b1, sg_b2, seb, ws, out);
    } else {
        pointnet_body(smem, blk - 1024, pts, p_w1, p_b1, p_b2, p_b3, ws, oeb, out);
    }
}

extern "C" void kernel_launch(void* const* d_in, const int* in_sizes, int n_in,
                              void* d_out, int out_size, void* d_ws, size_t ws_size,
                              hipStream_t stream) {
    (void)in_sizes; (void)n_in; (void)out_size; (void)ws_size;
    const float* tot_pts  = (const float*)d_in[0];
    const float* src_feat = (const float*)d_in[1];
    const float* ref_feat = (const float*)d_in[2];
    const float* sg_w1 = (const float*)d_in[6];
    const float* sg_b1 = (const float*)d_in[7];
    const float* sg_w2 = (const float*)d_in[8];
    const float* sg_b2 = (const float*)d_in[9];
    const float* se_w  = (const float*)d_in[10];
    const float* se_b  = (const float*)d_in[11];
    const float* p_w1  = (const float*)d_in[12];
    const float* p_b1  = (const float*)d_in[13];
    const float* p_w2  = (const float*)d_in[14];
    const float* p_b2  = (const float*)d_in[15];
    const float* p_w3  = (const float*)d_in[16];
    const float* p_b3  = (const float*)d_in[17];
    const float* oe_w  = (const float*)d_in[18];
    const float* oe_b  = (const float*)d_in[19];
    float* out = (float*)d_out;
    unsigned short* ws = (unsigned short*)d_ws;

    prep_kernel<<<(WS_TOT + 255) / 256, 256, 0, stream>>>(
        p_w2, p_w3, oe_w, sg_w1, sg_w2, se_w, ws);
    fused_kernel<<<1024 + N_TOT, 256, 0, stream>>>(
        tot_pts, src_feat, ref_feat, sg_b1, sg_b2, se_b,
        p_w1, p_b1, p_b2, p_b3, oe_b, ws, out);
}